// Round 2
// baseline (337.852 us; speedup 1.0000x reference)
//
#include <hip/hip_runtime.h>

#define N_PMT 180
#define N_PMT4 45          // 180 floats = 45 float4 per vis row (720 B, 16B-aligned)
#define N_CLUSTERS 128
#define NBINS 512          // sort buckets: vox >> 9
#define BPC 16             // gather blocks per cluster (chunk = 512 points)
#define BLOCK 256
#define NWAVE (BLOCK / 64)
#define PIPE 8             // software-pipeline depth (rows in flight)
#define SORT_T 1024
#define SORT_CAP 8192      // max points per cluster held in LDS (64 KB)

// ---- workspace layout (bytes) ----
// 0       : int   offsC[N_CLUSTERS+1]
// 1024    : float dxc[N_CLUSTERS]        (fallback path only)
// 2048    : uint2 sorted[n]  (vox, q_bits) bucket-sorted within cluster

// ---------------- fused voxelize + counting sort, one block per cluster ------
__global__ __launch_bounds__(SORT_T) void k_voxsort(
    const float4* __restrict__ batch,
    const float*  __restrict__ dx,
    const int*    __restrict__ sizes,
    const float*  __restrict__ dx_ranges,
    int*          __restrict__ offsC,
    uint2*        __restrict__ sorted) {

    __shared__ uint2 svq[SORT_CAP];                       // 64 KB
    __shared__ int hist[NBINS], sa[NBINS], sb[NBINS], cur[NBINS];  // 8 KB
    __shared__ int sSz[N_CLUSTERS];
    __shared__ int sE0, sCnt;

    const int c = blockIdx.x, t = threadIdx.x;
    if (t < N_CLUSTERS) sSz[t] = sizes[t];
    if (t < NBINS) hist[t] = 0;
    __syncthreads();
    if (t == 0) {
        int acc = 0;
        for (int i = 0; i < c; ++i) acc += sSz[i];
        sE0 = acc; sCnt = sSz[c];
        offsC[c] = acc;                                   // k_gather reads these
        if (c == N_CLUSTERS - 1) offsC[N_CLUSTERS] = acc + sSz[c];
    }
    __syncthreads();
    const int e0 = sE0, cnt = sCnt;
    const float lo = dx_ranges[2 * c], hi = dx_ranges[2 * c + 1];
    const float dxcc = fminf(fmaxf(dx[c], lo), hi);
    const bool fits = (cnt <= SORT_CAP);                  // wave-uniform

    for (int i = t; i < cnt; i += SORT_T) {
        float4 pd = batch[e0 + i];
        int ix = max(0, min(63, (int)floorf(pd.x + dxcc)));
        int iy = max(0, min(63, (int)floorf(pd.y)));
        int iz = max(0, min(63, (int)floorf(pd.z)));
        unsigned vox = (unsigned)(ix + 64 * (iy + 64 * iz));
        if (fits) svq[i] = make_uint2(vox, __float_as_uint(pd.w));
        atomicAdd(&hist[vox >> 9], 1);
    }
    __syncthreads();
    if (t < NBINS) sa[t] = hist[t];
    __syncthreads();
    int* src = sa; int* dst = sb;
    for (int d = 1; d < NBINS; d <<= 1) {                 // Hillis-Steele inclusive scan
        if (t < NBINS) dst[t] = src[t] + (t >= d ? src[t - d] : 0);
        __syncthreads();
        int* tmp = src; src = dst; dst = tmp;
    }
    if (t < NBINS) cur[t] = src[t] - hist[t];             // exclusive
    __syncthreads();
    if (fits) {
        for (int i = t; i < cnt; i += SORT_T) {
            uint2 e = svq[i];
            int pos = atomicAdd(&cur[e.x >> 9], 1);
            sorted[e0 + pos] = e;
        }
    } else {                                              // general-size: re-read batch
        for (int i = t; i < cnt; i += SORT_T) {
            float4 pd = batch[e0 + i];
            int ix = max(0, min(63, (int)floorf(pd.x + dxcc)));
            int iy = max(0, min(63, (int)floorf(pd.y)));
            int iz = max(0, min(63, (int)floorf(pd.z)));
            unsigned vox = (unsigned)(ix + 64 * (iy + 64 * iz));
            int pos = atomicAdd(&cur[vox >> 9], 1);
            sorted[e0 + pos] = make_uint2(vox, __float_as_uint(pd.w));
        }
    }
}

// ---------------- gather: XCD-localized vis slices + deep row pipeline -------
__global__ __launch_bounds__(BLOCK, 4) void k_gather(
    const uint2*  __restrict__ sorted,
    const float4* __restrict__ vis4,
    const int*    __restrict__ offsC,
    float* __restrict__ out) {

    // XCD-aware remap. Consecutive blockIdx round-robin across the 8 XCDs,
    // so x = blockIdx&7 is the XCD id. Give each XCD two 'sub' slices across
    // ALL clusters: the ~5.3x cross-cluster reuse of each vis row then hits
    // this XCD's private 4MB L2 instead of re-crossing the fabric 8x.
    const int x   = blockIdx.x & 7;        // XCD id (round-robin assumption)
    const int i   = blockIdx.x >> 3;       // 0..255 within this XCD
    const int sub = 2 * x + (i & 1);       // 16 subs -> 2 per XCD
    const int c   = i >> 1;                // 0..127 clusters

    const int start = offsC[c], end = offsC[c + 1];
    const int count = end - start;
    const int chunk = (count + BPC - 1) / BPC;
    const int s0 = start + sub * chunk;
    const int s1 = min(s0 + chunk, end);

    const int wave = threadIdx.x >> 6, lane = threadIdx.x & 63;
    const int wtotal = s1 - s0;
    const int per = (wtotal + NWAVE - 1) / NWAVE;
    const int ws0 = s0 + wave * per;
    const int ws1 = min(ws0 + per, s1);

    const int lclamp = min(lane, N_PMT4 - 1);    // branchless: lanes 45..63 dup lane 44

    float4 accE = {0.f, 0.f, 0.f, 0.f};
    float4 accO = {0.f, 0.f, 0.f, 0.f};

    for (int base = ws0; base < ws1; base += 64) {
        const int p = base + lane;
        uint2 se = (p < ws1) ? sorted[p] : make_uint2(0u, 0u);  // pad: q=0
        const int   vox = (int)se.x;
        const float q   = __uint_as_float(se.y);

        // ---- software-pipelined row loads: issue batch j+1 before consuming batch j
        float4 rc[PIPE];
        #pragma unroll
        for (int jj = 0; jj < PIPE; ++jj) {
            const int v = __builtin_amdgcn_readlane(vox, jj);
            rc[jj] = vis4[(size_t)v * N_PMT4 + lclamp];
        }
        #pragma unroll
        for (int j0 = 0; j0 < 64; j0 += PIPE) {
            float4 rn[PIPE];
            if (j0 + PIPE < 64) {
                #pragma unroll
                for (int jj = 0; jj < PIPE; ++jj) {
                    const int v = __builtin_amdgcn_readlane(vox, j0 + PIPE + jj);
                    rn[jj] = vis4[(size_t)v * N_PMT4 + lclamp];
                }
            }
            #pragma unroll
            for (int jj = 0; jj < PIPE; ++jj) {
                const float qq = __uint_as_float(
                    __builtin_amdgcn_readlane(__float_as_uint(q), j0 + jj));
                if (jj & 1) {
                    accO.x = fmaf(rc[jj].x, qq, accO.x);
                    accO.y = fmaf(rc[jj].y, qq, accO.y);
                    accO.z = fmaf(rc[jj].z, qq, accO.z);
                    accO.w = fmaf(rc[jj].w, qq, accO.w);
                } else {
                    accE.x = fmaf(rc[jj].x, qq, accE.x);
                    accE.y = fmaf(rc[jj].y, qq, accE.y);
                    accE.z = fmaf(rc[jj].z, qq, accE.z);
                    accE.w = fmaf(rc[jj].w, qq, accE.w);
                }
            }
            #pragma unroll
            for (int jj = 0; jj < PIPE; ++jj) rc[jj] = rn[jj];  // renamed under full unroll
        }
    }

    // per-wave private LDS rows (no float LDS atomics), then one global atomic per PMT
    __shared__ float sacc[NWAVE][184];
    if (lane < N_PMT4) {
        sacc[wave][lane * 4 + 0] = accE.x + accO.x;
        sacc[wave][lane * 4 + 1] = accE.y + accO.y;
        sacc[wave][lane * 4 + 2] = accE.z + accO.z;
        sacc[wave][lane * 4 + 3] = accE.w + accO.w;
    }
    __syncthreads();
    for (int i2 = threadIdx.x; i2 < N_PMT; i2 += BLOCK) {
        float s = sacc[0][i2] + sacc[1][i2] + sacc[2][i2] + sacc[3][i2];
        atomicAdd(&out[c * N_PMT + i2], s);
    }
}

// ---------------- fallback (unsorted point-major) ----------------
__global__ void prep_kernel(const float* __restrict__ dx,
                            const int* __restrict__ sizes,
                            const float* __restrict__ dx_ranges,
                            int* __restrict__ offsC,
                            float* __restrict__ dxc) {
    __shared__ int s[N_CLUSTERS];
    const int t = threadIdx.x;      // 128 threads
    s[t] = sizes[t];
    float lo = dx_ranges[2 * t];
    float hi = dx_ranges[2 * t + 1];
    dxc[t] = fminf(fmaxf(dx[t], lo), hi);
    __syncthreads();
    int acc = 0;
    for (int i = 0; i < t; ++i) acc += s[i];
    offsC[t] = acc;
    if (t == N_CLUSTERS - 1) offsC[N_CLUSTERS] = acc + s[t];
}

__global__ __launch_bounds__(BLOCK) void gather_kernel(
    const float4* __restrict__ batch,
    const float4* __restrict__ vis4,
    const int*    __restrict__ offsets,
    const float*  __restrict__ dxc,
    float* __restrict__ out) {
    const int b = blockIdx.x;
    const int c = b / 16, sub = b % 16;
    const int start = offsets[c], end = offsets[c + 1];
    const int count = end - start;
    const int chunk = (count + 15) / 16;
    const int s0 = start + sub * chunk;
    const int s1 = min(s0 + chunk, end);
    const int wave = threadIdx.x >> 6, lane = threadIdx.x & 63;
    const int wtotal = s1 - s0;
    const int per = (wtotal + NWAVE - 1) / NWAVE;
    const int ws0 = s0 + wave * per;
    const int ws1 = min(ws0 + per, s1);
    const float dxc_c = dxc[c];
    const bool active = (lane < N_PMT4);
    float4 accE = {0.f, 0.f, 0.f, 0.f};
    for (int base = ws0; base < ws1; base += 64) {
        const int p = base + lane;
        float q = 0.f; int vox = 0;
        if (p < ws1) {
            float4 pd = batch[p];
            int ix = max(0, min(63, (int)floorf(pd.x + dxc_c)));
            int iy = max(0, min(63, (int)floorf(pd.y)));
            int iz = max(0, min(63, (int)floorf(pd.z)));
            vox = ix + 64 * (iy + 64 * iz);
            q = pd.w;
        }
        #pragma unroll
        for (int j = 0; j < 64; ++j) {
            const int   v  = __builtin_amdgcn_readlane(vox, j);
            const float qj = __uint_as_float(__builtin_amdgcn_readlane(__float_as_uint(q), j));
            if (active) {
                float4 r = vis4[(size_t)v * N_PMT4 + lane];
                accE.x = fmaf(r.x, qj, accE.x);
                accE.y = fmaf(r.y, qj, accE.y);
                accE.z = fmaf(r.z, qj, accE.z);
                accE.w = fmaf(r.w, qj, accE.w);
            }
        }
    }
    __shared__ float sacc[N_PMT];
    for (int i = threadIdx.x; i < N_PMT; i += BLOCK) sacc[i] = 0.f;
    __syncthreads();
    if (active) {
        atomicAdd(&sacc[lane * 4 + 0], accE.x);
        atomicAdd(&sacc[lane * 4 + 1], accE.y);
        atomicAdd(&sacc[lane * 4 + 2], accE.z);
        atomicAdd(&sacc[lane * 4 + 3], accE.w);
    }
    __syncthreads();
    for (int i = threadIdx.x; i < N_PMT; i += BLOCK)
        atomicAdd(&out[c * N_PMT + i], sacc[i]);
}

extern "C" void kernel_launch(void* const* d_in, const int* in_sizes, int n_in,
                              void* d_out, int out_size, void* d_ws, size_t ws_size,
                              hipStream_t stream) {
    const float* dx        = (const float*)d_in[0];
    const float* batch     = (const float*)d_in[1];
    const int*   sizes     = (const int*)d_in[2];
    const float* dx_ranges = (const float*)d_in[3];
    const float* vis       = (const float*)d_in[4];
    float* out = (float*)d_out;
    char*  wsb = (char*)d_ws;
    const int n = in_sizes[1] / 4;   // total points

    int*   offsC  = (int*)(wsb + 0);
    float* dxc    = (float*)(wsb + 1024);
    uint2* sorted = (uint2*)(wsb + 2048);

    hipMemsetAsync(out, 0, (size_t)out_size * sizeof(float), stream);

    const size_t need = 2048ull + 8ull * (size_t)n;
    if (ws_size >= need) {
        k_voxsort<<<N_CLUSTERS, SORT_T, 0, stream>>>(
            (const float4*)batch, dx, sizes, dx_ranges, offsC, sorted);
        k_gather<<<N_CLUSTERS * BPC, BLOCK, 0, stream>>>(
            sorted, (const float4*)vis, offsC, out);
    } else {
        prep_kernel<<<1, N_CLUSTERS, 0, stream>>>(dx, sizes, dx_ranges, offsC, dxc);
        gather_kernel<<<N_CLUSTERS * 16, BLOCK, 0, stream>>>(
            (const float4*)batch, (const float4*)vis, offsC, dxc, out);
    }
}

// Round 3
// 334.560 us; speedup vs baseline: 1.0098x; 1.0098x over previous
//
#include <hip/hip_runtime.h>

#define N_PMT 180
#define N_PMT4 45            // 180 floats = 45 float4 per vis row (720 B)
#define N_CLUSTERS 128
#define NBINS 2048           // sort bins: vox >> 7  (128-voxel x-slabs)
#define SLICE_VOX 128
#define SPB 8                // slices per gather block (2048 / 256)
#define GBLK 256             // gather blocks (1 per CU)
#define GT 1024              // gather threads per block
#define GW 16                // waves per gather block
#define CPW 8                // clusters per wave (128 / 16)
#define SORT_T 1024
#define SORT_CAP 8192        // max points per cluster held in LDS (64 KB)
#define BLOCK 256
#define NWAVE (BLOCK / 64)

// ---- workspace layout (bytes) ----
// 0       : int   offsC[N_CLUSTERS+1]
// 1024    : float dxc[N_CLUSTERS]                  (fallback path only)
// 2048    : int   bucketOffs[128][NBINS+1]         (1,049,088 B)
// +BO     : uint2 sorted[n]                        (vox, q_bits) slice-sorted per cluster
// +8n     : float partial[GBLK][128][180]          (23,592,960 B, if ws permits)

// ---------------- fused voxelize + 2048-bin counting sort, 1 block/cluster ---
__global__ __launch_bounds__(SORT_T) void k_voxsort(
    const float4* __restrict__ batch,
    const float*  __restrict__ dx,
    const int*    __restrict__ sizes,
    const float*  __restrict__ dx_ranges,
    int*          __restrict__ offsC,
    int*          __restrict__ bucketOffs,
    uint2*        __restrict__ sorted) {

    __shared__ uint2 svq[SORT_CAP];            // 64 KB
    __shared__ int hist[NBINS];                // 8 KB
    __shared__ int cur[NBINS];                 // 8 KB
    __shared__ int tsA[SORT_T], tsB[SORT_T];   // 8 KB
    __shared__ int sSz[N_CLUSTERS];
    __shared__ int sE0;

    const int c = blockIdx.x, t = threadIdx.x;
    if (t < N_CLUSTERS) sSz[t] = sizes[t];
    hist[2*t] = 0; hist[2*t+1] = 0;
    __syncthreads();
    if (t == 0) {
        int acc = 0;
        for (int i = 0; i < c; ++i) acc += sSz[i];
        sE0 = acc;
        offsC[c] = acc;
        if (c == N_CLUSTERS - 1) offsC[N_CLUSTERS] = acc + sSz[c];
    }
    __syncthreads();
    const int e0 = sE0, cnt = sSz[c];
    const float lo = dx_ranges[2*c], hi = dx_ranges[2*c+1];
    const float dxcc = fminf(fmaxf(dx[c], lo), hi);
    const bool fits = (cnt <= SORT_CAP);       // wave-uniform

    for (int i = t; i < cnt; i += SORT_T) {
        float4 pd = batch[e0 + i];
        int ix = max(0, min(63, (int)floorf(pd.x + dxcc)));
        int iy = max(0, min(63, (int)floorf(pd.y)));
        int iz = max(0, min(63, (int)floorf(pd.z)));
        unsigned vox = (unsigned)(ix + 64 * (iy + 64 * iz));
        if (fits) svq[i] = make_uint2(vox, __float_as_uint(pd.w));
        atomicAdd(&hist[vox >> 7], 1);
    }
    __syncthreads();
    // scan: thread t owns bins 2t, 2t+1
    const int h0 = hist[2*t], h1 = hist[2*t+1];
    const int tsum = h0 + h1;
    tsA[t] = tsum;
    __syncthreads();
    int* src = tsA; int* dst = tsB;
    for (int d = 1; d < SORT_T; d <<= 1) {     // Hillis-Steele inclusive over 1024
        dst[t] = src[t] + (t >= d ? src[t - d] : 0);
        __syncthreads();
        int* tmp = src; src = dst; dst = tmp;
    }
    const int texcl = src[t] - tsum;           // exclusive prefix of this thread's pair
    cur[2*t]   = texcl;
    cur[2*t+1] = texcl + h0;
    {
        int* bo = bucketOffs + (size_t)c * (NBINS + 1);
        bo[2*t]   = e0 + texcl;
        bo[2*t+1] = e0 + texcl + h0;
        if (t == SORT_T - 1) bo[NBINS] = e0 + cnt;
    }
    __syncthreads();
    if (fits) {
        for (int i = t; i < cnt; i += SORT_T) {
            uint2 e = svq[i];
            int pos = atomicAdd(&cur[e.x >> 7], 1);
            sorted[e0 + pos] = e;
        }
    } else {                                   // general-size: re-read batch
        for (int i = t; i < cnt; i += SORT_T) {
            float4 pd = batch[e0 + i];
            int ix = max(0, min(63, (int)floorf(pd.x + dxcc)));
            int iy = max(0, min(63, (int)floorf(pd.y)));
            int iz = max(0, min(63, (int)floorf(pd.z)));
            unsigned vox = (unsigned)(ix + 64 * (iy + 64 * iz));
            int pos = atomicAdd(&cur[vox >> 7], 1);
            sorted[e0 + pos] = make_uint2(vox, __float_as_uint(pd.w));
        }
    }
}

// ---------------- LDS-staged slice gather: 256 persistent blocks ------------
// Block b owns slices [b*SPB, b*SPB+SPB). Per slice: stage the 128-voxel vis
// slab (90 KB) into LDS once, then each wave accumulates its 8 clusters'
// points from LDS into registers. vis crosses the TA exactly once, coalesced.
__global__ __launch_bounds__(GT, 4) void k_slice(
    const uint2*  __restrict__ sorted,
    const float4* __restrict__ vis4,
    const int*    __restrict__ bucketOffs,
    float* __restrict__ out,
    float* __restrict__ partial,
    const int usePartial) {

    __shared__ float4 vtile[SLICE_VOX * N_PMT4];   // 92,160 B
    __shared__ int offs[N_CLUSTERS][SPB + 1];      // 4,608 B

    const int b = blockIdx.x;
    const int s0 = b * SPB;
    const int t = threadIdx.x;
    const int wave = t >> 6, lane = t & 63;
    const int lclamp = min(lane, N_PMT4 - 1);      // lanes 45..63 dup lane 44
    const int cbase = wave * CPW;

    // stage per-(cluster, slice) segment offsets for this block
    for (int i = t; i < N_CLUSTERS * (SPB + 1); i += GT) {
        const int c = i / (SPB + 1), j = i - c * (SPB + 1);
        offs[c][j] = bucketOffs[(size_t)c * (NBINS + 1) + s0 + j];
    }

    float4 acc[CPW];
    #pragma unroll
    for (int k = 0; k < CPW; ++k) acc[k] = make_float4(0.f, 0.f, 0.f, 0.f);

    for (int s = 0; s < SPB; ++s) {
        __syncthreads();                            // vtile free; offs ready (s==0)
        const float4* srcv = vis4 + (size_t)(s0 + s) * (SLICE_VOX * N_PMT4);
        for (int i = t; i < SLICE_VOX * N_PMT4; i += GT) vtile[i] = srcv[i];
        __syncthreads();

        // wave-load first chunk of all 8 segments up-front (independent loads)
        uint2 rec[CPW]; int lo_[CPW], hi_[CPW], m_[CPW];
        #pragma unroll
        for (int k = 0; k < CPW; ++k) {
            const int c = cbase + k;
            lo_[k] = offs[c][s]; hi_[k] = offs[c][s + 1];
            const int m = min(hi_[k] - lo_[k], 64);
            m_[k] = m;
            const int p = (m > 0) ? lo_[k] + min(lane, m - 1) : 0;
            rec[k] = sorted[p];
            if (lane >= m) rec[k].y = 0u;           // pad lanes: q = 0, vox stays valid
        }

        #pragma unroll
        for (int k = 0; k < CPW; ++k) {
            const int m = m_[k];
            if (m > 0) {
                const int vx = (int)rec[k].x;
                const int qy = (int)rec[k].y;
                #define ROWJ(J) vtile[(__builtin_amdgcn_readlane(vx, (J)) & (SLICE_VOX - 1)) * N_PMT4 + lclamp]
                float4 r0 = ROWJ(0);
                float4 r1 = ROWJ(m > 1 ? 1 : 0);
                for (int j = 0; j < m; j += 2) {
                    const int j2 = (j + 2 < 63) ? j + 2 : 63;
                    const int j3 = (j + 3 < 63) ? j + 3 : 63;
                    float4 n0 = ROWJ(j2);           // depth-2 row prefetch
                    float4 n1 = ROWJ(j3);
                    const float q0 = __uint_as_float(__builtin_amdgcn_readlane(qy, j));
                    const float q1 = __uint_as_float(__builtin_amdgcn_readlane(qy, j + 1));
                    acc[k].x = fmaf(r0.x, q0, acc[k].x);
                    acc[k].y = fmaf(r0.y, q0, acc[k].y);
                    acc[k].z = fmaf(r0.z, q0, acc[k].z);
                    acc[k].w = fmaf(r0.w, q0, acc[k].w);
                    acc[k].x = fmaf(r1.x, q1, acc[k].x);
                    acc[k].y = fmaf(r1.y, q1, acc[k].y);
                    acc[k].z = fmaf(r1.z, q1, acc[k].z);
                    acc[k].w = fmaf(r1.w, q1, acc[k].w);
                    r0 = n0; r1 = n1;
                }
                #undef ROWJ
                // rare tail: segment longer than 64 points
                for (int base = lo_[k] + 64; base < hi_[k]; base += 64) {
                    const int mm = min(hi_[k] - base, 64);
                    uint2 rr = sorted[base + min(lane, mm - 1)];
                    if (lane >= mm) rr.y = 0u;
                    const int vx2 = (int)rr.x, qy2 = (int)rr.y;
                    for (int j = 0; j < mm; ++j) {
                        const float qj = __uint_as_float(__builtin_amdgcn_readlane(qy2, j));
                        const float4 r = vtile[(__builtin_amdgcn_readlane(vx2, j) & (SLICE_VOX - 1)) * N_PMT4 + lclamp];
                        acc[k].x = fmaf(r.x, qj, acc[k].x);
                        acc[k].y = fmaf(r.y, qj, acc[k].y);
                        acc[k].z = fmaf(r.z, qj, acc[k].z);
                        acc[k].w = fmaf(r.w, qj, acc[k].w);
                    }
                }
            }
        }
    }

    // flush: non-atomic per-block partial (preferred) or atomics to out
    if (usePartial) {
        float* pdst = partial + (size_t)b * (N_CLUSTERS * N_PMT);
        if (lane < N_PMT4) {
            #pragma unroll
            for (int k = 0; k < CPW; ++k) {
                float4* dst4 = reinterpret_cast<float4*>(pdst + (size_t)(cbase + k) * N_PMT);
                dst4[lane] = acc[k];
            }
        }
    } else {
        if (lane < N_PMT4) {
            #pragma unroll
            for (int k = 0; k < CPW; ++k) {
                float* dst = out + (size_t)(cbase + k) * N_PMT + 4 * lane;
                atomicAdd(dst + 0, acc[k].x);
                atomicAdd(dst + 1, acc[k].y);
                atomicAdd(dst + 2, acc[k].z);
                atomicAdd(dst + 3, acc[k].w);
            }
        }
    }
}

__global__ void k_reduce(const float* __restrict__ partial, float* __restrict__ out) {
    const int i = blockIdx.x * 256 + threadIdx.x;
    if (i >= N_CLUSTERS * N_PMT) return;
    float s = 0.f;
    for (int b = 0; b < GBLK; ++b)
        s += partial[(size_t)b * (N_CLUSTERS * N_PMT) + i];
    out[i] = s;
}

// ---------------- fallback (unsorted point-major) ----------------
__global__ void prep_kernel(const float* __restrict__ dx,
                            const int* __restrict__ sizes,
                            const float* __restrict__ dx_ranges,
                            int* __restrict__ offsC,
                            float* __restrict__ dxc) {
    __shared__ int s[N_CLUSTERS];
    const int t = threadIdx.x;      // 128 threads
    s[t] = sizes[t];
    float lo = dx_ranges[2 * t];
    float hi = dx_ranges[2 * t + 1];
    dxc[t] = fminf(fmaxf(dx[t], lo), hi);
    __syncthreads();
    int acc = 0;
    for (int i = 0; i < t; ++i) acc += s[i];
    offsC[t] = acc;
    if (t == N_CLUSTERS - 1) offsC[N_CLUSTERS] = acc + s[t];
}

__global__ __launch_bounds__(BLOCK) void gather_kernel(
    const float4* __restrict__ batch,
    const float4* __restrict__ vis4,
    const int*    __restrict__ offsets,
    const float*  __restrict__ dxc,
    float* __restrict__ out) {
    const int b = blockIdx.x;
    const int c = b / 16, sub = b % 16;
    const int start = offsets[c], end = offsets[c + 1];
    const int count = end - start;
    const int chunk = (count + 15) / 16;
    const int s0 = start + sub * chunk;
    const int s1 = min(s0 + chunk, end);
    const int wave = threadIdx.x >> 6, lane = threadIdx.x & 63;
    const int wtotal = s1 - s0;
    const int per = (wtotal + NWAVE - 1) / NWAVE;
    const int ws0 = s0 + wave * per;
    const int ws1 = min(ws0 + per, s1);
    const float dxc_c = dxc[c];
    const bool active = (lane < N_PMT4);
    float4 accE = {0.f, 0.f, 0.f, 0.f};
    for (int base = ws0; base < ws1; base += 64) {
        const int p = base + lane;
        float q = 0.f; int vox = 0;
        if (p < ws1) {
            float4 pd = batch[p];
            int ix = max(0, min(63, (int)floorf(pd.x + dxc_c)));
            int iy = max(0, min(63, (int)floorf(pd.y)));
            int iz = max(0, min(63, (int)floorf(pd.z)));
            vox = ix + 64 * (iy + 64 * iz);
            q = pd.w;
        }
        #pragma unroll
        for (int j = 0; j < 64; ++j) {
            const int   v  = __builtin_amdgcn_readlane(vox, j);
            const float qj = __uint_as_float(__builtin_amdgcn_readlane(__float_as_uint(q), j));
            if (active) {
                float4 r = vis4[(size_t)v * N_PMT4 + lane];
                accE.x = fmaf(r.x, qj, accE.x);
                accE.y = fmaf(r.y, qj, accE.y);
                accE.z = fmaf(r.z, qj, accE.z);
                accE.w = fmaf(r.w, qj, accE.w);
            }
        }
    }
    __shared__ float sacc[N_PMT];
    for (int i = threadIdx.x; i < N_PMT; i += BLOCK) sacc[i] = 0.f;
    __syncthreads();
    if (active) {
        atomicAdd(&sacc[lane * 4 + 0], accE.x);
        atomicAdd(&sacc[lane * 4 + 1], accE.y);
        atomicAdd(&sacc[lane * 4 + 2], accE.z);
        atomicAdd(&sacc[lane * 4 + 3], accE.w);
    }
    __syncthreads();
    for (int i = threadIdx.x; i < N_PMT; i += BLOCK)
        atomicAdd(&out[c * N_PMT + i], sacc[i]);
}

extern "C" void kernel_launch(void* const* d_in, const int* in_sizes, int n_in,
                              void* d_out, int out_size, void* d_ws, size_t ws_size,
                              hipStream_t stream) {
    const float* dx        = (const float*)d_in[0];
    const float* batch     = (const float*)d_in[1];
    const int*   sizes     = (const int*)d_in[2];
    const float* dx_ranges = (const float*)d_in[3];
    const float* vis       = (const float*)d_in[4];
    float* out = (float*)d_out;
    char*  wsb = (char*)d_ws;
    const int n = in_sizes[1] / 4;   // total points

    int*   offsC      = (int*)(wsb + 0);
    float* dxc        = (float*)(wsb + 1024);
    int*   bucketOffs = (int*)(wsb + 2048);
    const size_t BO_BYTES   = (size_t)N_CLUSTERS * (NBINS + 1) * 4;          // 1,049,088
    uint2* sorted     = (uint2*)(wsb + 2048 + BO_BYTES);
    const size_t need1      = 2048 + BO_BYTES + 8ull * (size_t)n;
    float* partial    = (float*)(wsb + need1);
    const size_t PART_BYTES = (size_t)GBLK * N_CLUSTERS * N_PMT * 4;         // 23,592,960
    const size_t need2      = need1 + PART_BYTES;

    hipMemsetAsync(out, 0, (size_t)out_size * sizeof(float), stream);

    if (ws_size >= need1) {
        const int usePartial = (ws_size >= need2) ? 1 : 0;
        k_voxsort<<<N_CLUSTERS, SORT_T, 0, stream>>>(
            (const float4*)batch, dx, sizes, dx_ranges, offsC, bucketOffs, sorted);
        k_slice<<<GBLK, GT, 0, stream>>>(
            sorted, (const float4*)vis, bucketOffs, out,
            usePartial ? partial : out, usePartial);
        if (usePartial)
            k_reduce<<<(N_CLUSTERS * N_PMT + 255) / 256, 256, 0, stream>>>(partial, out);
    } else {
        prep_kernel<<<1, N_CLUSTERS, 0, stream>>>(dx, sizes, dx_ranges, offsC, dxc);
        gather_kernel<<<N_CLUSTERS * 16, BLOCK, 0, stream>>>(
            (const float4*)batch, (const float4*)vis, offsC, dxc, out);
    }
}